// Round 3
// baseline (209.733 us; speedup 1.0000x reference)
//
#include <hip/hip_runtime.h>
#include <hip/hip_bf16.h>

// B=4, S=2048, D=1024 causal attention, fp32 in/out, bf16 MFMA compute.
#define BB 4
#define SS 2048
#define DD 1024

typedef __attribute__((ext_vector_type(8))) short bf16x8;
typedef __attribute__((ext_vector_type(4))) float f32x4;
typedef __attribute__((ext_vector_type(8))) unsigned short u16x8;

__device__ __forceinline__ ushort f2bf(float f) {
  unsigned u = __float_as_uint(f);
  unsigned r = (u + 0x7fffu + ((u >> 16) & 1u)) >> 16;  // RNE
  return (ushort)r;
}

__device__ __forceinline__ void gload_lds16(const void* g, void* l) {
  __builtin_amdgcn_global_load_lds(
      (const __attribute__((address_space(1))) void*)g,
      (__attribute__((address_space(3))) void*)l, 16, 0, 0);
}

__device__ __forceinline__ void fence_bar() {
  __builtin_amdgcn_sched_barrier(0);
  __builtin_amdgcn_s_barrier();
  __builtin_amdgcn_sched_barrier(0);
}

// ---------------------------------------------------------------- cast x -> bf16
__global__ __launch_bounds__(256) void cast_x_kernel(const float* __restrict__ x,
                                                     ushort* __restrict__ xb) {
  const int i = blockIdx.x * 256 + threadIdx.x;
  const float4 a = ((const float4*)x)[2 * i];
  const float4 b = ((const float4*)x)[2 * i + 1];
  ushort4 o0, o1;
  o0.x = f2bf(a.x); o0.y = f2bf(a.y); o0.z = f2bf(a.z); o0.w = f2bf(a.w);
  o1.x = f2bf(b.x); o1.y = f2bf(b.y); o1.z = f2bf(b.z); o1.w = f2bf(b.w);
  ((ushort4*)xb)[2 * i] = o0;
  ((ushort4*)xb)[2 * i + 1] = o1;
}

// ------------------------------------------- cast + transpose W [K,N] -> Wt [N,K] bf16
__global__ __launch_bounds__(256) void cast_transpose_w(const float* __restrict__ W0,
                                                        const float* __restrict__ W1,
                                                        const float* __restrict__ W2,
                                                        ushort* __restrict__ Wt) {
  const float* W = blockIdx.z == 0 ? W0 : (blockIdx.z == 1 ? W1 : W2);
  ushort* O = Wt + (size_t)blockIdx.z * DD * DD;
  __shared__ ushort t[32][33];
  const int n0 = blockIdx.x * 32, k0 = blockIdx.y * 32;
  const int tx = threadIdx.x, ty = threadIdx.y;  // (32,8)
#pragma unroll
  for (int j = 0; j < 4; j++) {
    int k = k0 + ty + j * 8;
    t[ty + j * 8][tx] = f2bf(W[(size_t)k * DD + n0 + tx]);
  }
  __syncthreads();
#pragma unroll
  for (int j = 0; j < 4; j++) {
    int n = ty + j * 8;
    O[(size_t)(n0 + n) * DD + k0 + tx] = t[tx][n];
  }
}

// ------------------------------------------- transpose V [S,ldv slice] -> Vt [D,S] per batch
__global__ __launch_bounds__(256) void transpose_v(const ushort* __restrict__ V, int ldv,
                                                   ushort* __restrict__ Vt) {
  const int b = blockIdx.z;
  const ushort* Vb = V + (size_t)b * SS * ldv;
  ushort* Ob = Vt + (size_t)b * DD * SS;
  __shared__ ushort t[32][33];
  const int d0 = blockIdx.x * 32, s0 = blockIdx.y * 32;
  const int tx = threadIdx.x, ty = threadIdx.y;
#pragma unroll
  for (int j = 0; j < 4; j++) {
    int s = s0 + ty + j * 8;
    t[ty + j * 8][tx] = Vb[(size_t)s * ldv + d0 + tx];
  }
  __syncthreads();
#pragma unroll
  for (int j = 0; j < 4; j++) {
    int d = ty + j * 8;
    Ob[(size_t)(d0 + d) * SS + s0 + tx] = t[tx][d];
  }
}

// ---------------------------------------------------------------- 8-phase MFMA GEMM
// C[M,N] = A[M,K](bf16 rm) @ Bt[N,K](bf16 rm)^T. Tile 256x128, BK=64, 512 thr (8 waves 2Mx4N).
// LDS units (K-half-major): A-Kh 16KB [256][32], B-Kh 8KB [128][32]; double-buffered = 96KB.
// Per phase: {ds_read subtile; stage 1 unit; barrier; lgkmcnt(0); 8 MFMA; barrier}.
// Stage slots: phA: A-Kh1(T+1); phB: B-Kh0(T+2); phC: A-Kh0(T+2); phD: B-Kh1(T+2)+vmcnt(4).
// st_16x32 swizzle: LDS linear dest, inverse-swizzled global source, swizzled ds_read (rule 21).
#define QUAD8(AV, BV, MB)                                                    \
  do {                                                                       \
    __builtin_amdgcn_s_setprio(1);                                           \
    _Pragma("unroll") for (int i_ = 0; i_ < 4; i_++) {                       \
      _Pragma("unroll") for (int n_ = 0; n_ < 2; n_++) {                     \
        acc[(MB) + i_][n_] = __builtin_amdgcn_mfma_f32_16x16x32_bf16(        \
            AV[i_], BV[n_], acc[(MB) + i_][n_], 0, 0, 0);                    \
      }                                                                      \
    }                                                                        \
    __builtin_amdgcn_s_setprio(0);                                           \
  } while (0)

template <bool CAUSAL, bool KCLIP, bool OUT_BF16>
__global__ __launch_bounds__(512) void gemm8p(const ushort* __restrict__ A, int lda, size_t strA,
                                              const ushort* __restrict__ Bt, int ldb, size_t strB,
                                              void* __restrict__ C, int ldc, size_t strC, int K) {
  constexpr int BM = 256, BN = 128;
  // XCD-chunked bijective block swizzle (m204 form)
  const int gx = gridDim.x;
  const int nwg = gx * gridDim.y;
  int flat = blockIdx.y * gx + blockIdx.x;
  {
    int q = nwg >> 3, r = nwg & 7;
    int xcd = flat & 7, idx = flat >> 3;
    flat = (xcd < r ? xcd * (q + 1) : r * (q + 1) + (xcd - r) * q) + idx;
  }
  const int nb = flat % gx, mb = flat / gx, bz = blockIdx.z;
  if (CAUSAL && nb * BN > mb * BM + (BM - 1)) return;

  __shared__ char ldsA[2][2][16384];  // [dbuf][kh][256 rows x 32 elem]
  __shared__ char ldsB[2][2][8192];   // [dbuf][kh][128 rows x 32 elem]

  const int tid = threadIdx.x;
  const int lane = tid & 63, wid = tid >> 6;
  const int wr = wid >> 2, wc = wid & 3;   // 2M x 4N waves; wave tile 128x32
  const int fr = lane & 15, qq = lane >> 4;
  const int kxor = (qq * 16) ^ (((fr >> 3) & 1) << 5);  // swizzled k-byte within 64B row

  const ushort* Ag = A + (size_t)bz * strA + (size_t)mb * BM * lda;
  const ushort* Bg = Bt + (size_t)bz * strB + (size_t)nb * BN * ldb;
  // staging source (inverse swizzle): thread t -> row t>>2, colbyte ((t&3)*16)^(((t>>5)&1)<<5)
  const int srcColB = (((tid & 3) * 16) ^ (((tid >> 5) & 1) << 5)) >> 1;  // in elems
  const ushort* Ag_t = Ag + (size_t)(tid >> 2) * lda + srcColB;
  const ushort* Bg_t = Bg + (size_t)(tid >> 2) * ldb + srcColB;

  int kEnd = KCLIP ? (mb + 1) * BM : K;
  if (kEnd > K) kEnd = K;
  const int NT = kEnd >> 6;

  auto stageA = [&](int buf, int kh, int kt) {
#pragma unroll
    for (int j = 0; j < 2; j++)
      gload_lds16(Ag_t + (size_t)(j * 128) * lda + kt * 64 + kh * 32,
                  &ldsA[buf][kh][(tid + j * 512) * 16]);
  };
  auto stageB = [&](int buf, int kh, int kt) {
    gload_lds16(Bg_t + kt * 64 + kh * 32, &ldsB[buf][kh][tid * 16]);
  };
  auto ldA4 = [&](int buf, int kh, int mi0, bf16x8* o) {
#pragma unroll
    for (int i = 0; i < 4; i++)
      o[i] = *(const bf16x8*)(&ldsA[buf][kh][0] +
                              ((wr * 128 + (mi0 + i) * 16 + fr) << 6) + kxor);
  };
  auto ldB2 = [&](int buf, int kh, bf16x8* o) {
#pragma unroll
    for (int n = 0; n < 2; n++)
      o[n] = *(const bf16x8*)(&ldsB[buf][kh][0] +
                              ((wc * 32 + n * 16 + fr) << 6) + kxor);
  };

  // prologue: T0 all units (6 loads) + T1 {B0,A0,B1} (4 loads); retire T0, keep 4 in flight
  stageB(0, 0, 0); stageA(0, 0, 0); stageB(0, 1, 0); stageA(0, 1, 0);
  if (NT > 1) { stageB(1, 0, 1); stageA(1, 0, 1); stageB(1, 1, 1); }
  __builtin_amdgcn_sched_barrier(0);
  asm volatile("s_waitcnt vmcnt(4)" ::: "memory");
  fence_bar();

  f32x4 acc[8][2] = {};

  for (int t = 0; t < NT; ++t) {
    const int cur = t & 1;
    bf16x8 av[4], b0[2], b1[2];
    // ---- Phase A: (ks0, Mi0-3); stage A-Kh1(T+1) -> other buf
    ldA4(cur, 0, 0, av);
    ldB2(cur, 0, b0);
    if (t + 1 < NT) stageA(cur ^ 1, 1, t + 1);
    fence_bar();
    asm volatile("s_waitcnt lgkmcnt(0)" ::: "memory");
    __builtin_amdgcn_sched_barrier(0);
    QUAD8(av, b0, 0);
    fence_bar();
    // ---- Phase B: (ks0, Mi4-7); stage B-Kh0(T+2) -> cur buf (free: fully read at phase A)
    ldA4(cur, 0, 4, av);
    if (t + 2 < NT) stageB(cur, 0, t + 2);
    fence_bar();
    asm volatile("s_waitcnt lgkmcnt(0)" ::: "memory");
    __builtin_amdgcn_sched_barrier(0);
    QUAD8(av, b0, 4);
    fence_bar();
    // ---- Phase C: (ks1, Mi0-3); stage A-Kh0(T+2) (free after phase B)
    ldA4(cur, 1, 0, av);
    ldB2(cur, 1, b1);
    if (t + 2 < NT) stageA(cur, 0, t + 2);
    fence_bar();
    asm volatile("s_waitcnt lgkmcnt(0)" ::: "memory");
    __builtin_amdgcn_sched_barrier(0);
    QUAD8(av, b1, 0);
    fence_bar();
    // ---- Phase D: (ks1, Mi4-7); stage B-Kh1(T+2) (free after phase C); counted vmcnt gate
    ldA4(cur, 1, 4, av);
    __builtin_amdgcn_sched_barrier(0);
    if (t + 2 < NT) {
      stageB(cur, 1, t + 2);
      __builtin_amdgcn_sched_barrier(0);
      asm volatile("s_waitcnt vmcnt(4)" ::: "memory");  // retires ALL of T+1's units
    } else {
      asm volatile("s_waitcnt vmcnt(0)" ::: "memory");  // tail drain
    }
    fence_bar();
    asm volatile("s_waitcnt lgkmcnt(0)" ::: "memory");
    __builtin_amdgcn_sched_barrier(0);
    QUAD8(av, b1, 4);
    fence_bar();
  }

  // epilogue: C/D mapping col=lane&15, row=(lane>>4)*4+reg
  const int col0 = nb * BN + wc * 32 + fr;
  const int row00 = mb * BM + wr * 128 + qq * 4;
  if (OUT_BF16) {
    ushort* Cb = (ushort*)C + (size_t)bz * strC;
#pragma unroll
    for (int i = 0; i < 8; i++)
#pragma unroll
      for (int rr = 0; rr < 4; rr++) {
        size_t ro = (size_t)(row00 + i * 16 + rr) * ldc;
#pragma unroll
        for (int n = 0; n < 2; n++) Cb[ro + col0 + n * 16] = f2bf(acc[i][n][rr]);
      }
  } else {
    float* Cb = (float*)C + (size_t)bz * strC;
#pragma unroll
    for (int i = 0; i < 8; i++)
#pragma unroll
      for (int rr = 0; rr < 4; rr++) {
        size_t ro = (size_t)(row00 + i * 16 + rr) * ldc;
#pragma unroll
        for (int n = 0; n < 2; n++) Cb[ro + col0 + n * 16] = acc[i][n][rr];
      }
  }
}

// ---------------------------------------------------------------- single-pass causal softmax
// Sc: [B*S, S] bf16 raw scores (valid cols <= r). P: [B*S, S] bf16 normalized, zeros above diag.
__global__ __launch_bounds__(256) void softmax_causal(const ushort* __restrict__ Sc,
                                                      ushort* __restrict__ P) {
  const int row = blockIdx.x;
  const int r = row & (SS - 1);
  const ushort* srow = Sc + (size_t)row * SS;
  ushort* prow = P + (size_t)row * SS;
  const int tid = threadIdx.x;
  __shared__ float buf[SS];
  __shared__ float redm[4], reds[4];
  const float scale = 0.03125f;  // 1/sqrt(1024)
  const int nc = (r >> 3) + 1;   // 8-wide chunks containing valid cols

  float mx = -3.0e38f;
  for (int c8 = tid; c8 < nc; c8 += 256) {
    u16x8 v = ((const u16x8*)srow)[c8];
    int c = c8 * 8;
#pragma unroll
    for (int k = 0; k < 8; k++) {
      float f = __uint_as_float(((unsigned)v[k]) << 16);
      f = (c + k <= r) ? f * scale : -3.0e38f;
      buf[c + k] = f;
      mx = fmaxf(mx, f);
    }
  }
  const int lane = tid & 63, wid = tid >> 6;
#pragma unroll
  for (int off = 32; off > 0; off >>= 1) mx = fmaxf(mx, __shfl_down(mx, off));
  if (lane == 0) redm[wid] = mx;
  __syncthreads();
  mx = fmaxf(fmaxf(redm[0], redm[1]), fmaxf(redm[2], redm[3]));

  float sum = 0.f;
  for (int c = tid; c < nc * 8; c += 256) {
    float e = __expf(buf[c] - mx);
    buf[c] = e;
    sum += e;
  }
#pragma unroll
  for (int off = 32; off > 0; off >>= 1) sum += __shfl_down(sum, off);
  if (lane == 0) reds[wid] = sum;
  __syncthreads();
  sum = reds[0] + reds[1] + reds[2] + reds[3];
  const float inv = 1.0f / sum;
  __syncthreads();  // buf writes complete before reads below

  const int zs = nc * 8;
  for (int c8 = tid; c8 < SS / 8; c8 += 256) {
    int c = c8 * 8;
    u16x8 o;
    if (c < zs) {
#pragma unroll
      for (int k = 0; k < 8; k++) o[k] = f2bf(buf[c + k] * inv);
    } else {
#pragma unroll
      for (int k = 0; k < 8; k++) o[k] = 0;
    }
    ((u16x8*)prow)[c8] = o;
  }
}

// ---------------------------------------------------------------- launch
extern "C" void kernel_launch(void* const* d_in, const int* in_sizes, int n_in,
                              void* d_out, int out_size, void* d_ws, size_t ws_size,
                              hipStream_t stream) {
  const float* x = (const float*)d_in[0];
  const float* Wq = (const float*)d_in[1];
  const float* Wk = (const float*)d_in[2];
  const float* Wv = (const float*)d_in[3];

  char* ws = (char*)d_ws;
  // layout: xb @0 (16.7MB, reused by Vt) | Wt @16777216 (6.3MB) | QKV @23068672 (50.3MB,
  // reused by P) | Sc @73400320 (33.5MB bf16)
  ushort* xb = (ushort*)(ws);
  ushort* Wt = (ushort*)(ws + 16777216);
  ushort* QKV = (ushort*)(ws + 23068672);
  ushort* Sc = (ushort*)(ws + 73400320);
  ushort* P = (ushort*)(ws + 23068672);
  ushort* Vt = (ushort*)(ws);

  const size_t SD = (size_t)SS * DD;
  const size_t S2 = (size_t)SS * SS;
  const size_t SQ = (size_t)SS * 3072;

  cast_x_kernel<<<(BB * SS * DD) / (256 * 8), 256, 0, stream>>>(x, xb);
  cast_transpose_w<<<dim3(DD / 32, DD / 32, 3), dim3(32, 8), 0, stream>>>(Wq, Wk, Wv, Wt);
  // QKV projection: [8192,3072] = xb @ Wt^T   (768 blocks = 3 full rounds)
  gemm8p<false, false, true><<<dim3(3072 / 128, (BB * SS) / 256, 1), 512, 0, stream>>>(
      xb, DD, 0, Wt, DD, 0, QKV, 3072, 0, DD);
  transpose_v<<<dim3(DD / 32, SS / 32, BB), dim3(32, 8), 0, stream>>>(QKV + 2048, 3072, Vt);
  // scores = Q @ K^T (bf16 out, causal skip)   (288 active blocks)
  gemm8p<true, false, true><<<dim3(SS / 128, SS / 256, BB), 512, 0, stream>>>(
      QKV, 3072, SQ, QKV + 1024, 3072, SQ, Sc, SS, S2, DD);
  softmax_causal<<<BB * SS, 256, 0, stream>>>(Sc, P);
  // out = P @ Vt^T (f32), k-clipped   (256 blocks = 1 full round)
  gemm8p<false, true, false><<<dim3(DD / 128, SS / 256, BB), 512, 0, stream>>>(
      P, SS, S2, Vt, SS, SD, d_out, DD, SD, SS);

  (void)in_sizes; (void)n_in; (void)out_size; (void)ws_size;
}

// Round 4
// 206.393 us; speedup vs baseline: 1.0162x; 1.0162x over previous
//
#include <hip/hip_runtime.h>
#include <hip/hip_bf16.h>

// B=4, S=2048, D=1024 causal attention, fp32 in/out, bf16 MFMA compute.
#define BB 4
#define SS 2048
#define DD 1024

typedef __attribute__((ext_vector_type(8))) short bf16x8;
typedef __attribute__((ext_vector_type(4))) float f32x4;
typedef __attribute__((ext_vector_type(8))) unsigned short u16x8;

__device__ __forceinline__ ushort f2bf(float f) {
  unsigned u = __float_as_uint(f);
  unsigned r = (u + 0x7fffu + ((u >> 16) & 1u)) >> 16;  // RNE
  return (ushort)r;
}

__device__ __forceinline__ void gload_lds16(const void* g, void* l) {
  __builtin_amdgcn_global_load_lds(
      (const __attribute__((address_space(1))) void*)g,
      (__attribute__((address_space(3))) void*)l, 16, 0, 0);
}

__device__ __forceinline__ void fence_bar() {
  __builtin_amdgcn_sched_barrier(0);
  __builtin_amdgcn_s_barrier();
  __builtin_amdgcn_sched_barrier(0);
}

// ---------------------------------------------------------------- cast x -> bf16
__global__ __launch_bounds__(256) void cast_x_kernel(const float* __restrict__ x,
                                                     ushort* __restrict__ xb) {
  const int i = blockIdx.x * 256 + threadIdx.x;
  const float4 a = ((const float4*)x)[2 * i];
  const float4 b = ((const float4*)x)[2 * i + 1];
  ushort4 o0, o1;
  o0.x = f2bf(a.x); o0.y = f2bf(a.y); o0.z = f2bf(a.z); o0.w = f2bf(a.w);
  o1.x = f2bf(b.x); o1.y = f2bf(b.y); o1.z = f2bf(b.z); o1.w = f2bf(b.w);
  ((ushort4*)xb)[2 * i] = o0;
  ((ushort4*)xb)[2 * i + 1] = o1;
}

// ------------------------------------------- cast + transpose W [K,N] -> Wt [N,K] bf16
__global__ __launch_bounds__(256) void cast_transpose_w(const float* __restrict__ W0,
                                                        const float* __restrict__ W1,
                                                        const float* __restrict__ W2,
                                                        ushort* __restrict__ Wt) {
  const float* W = blockIdx.z == 0 ? W0 : (blockIdx.z == 1 ? W1 : W2);
  ushort* O = Wt + (size_t)blockIdx.z * DD * DD;
  __shared__ ushort t[32][33];
  const int n0 = blockIdx.x * 32, k0 = blockIdx.y * 32;
  const int tx = threadIdx.x, ty = threadIdx.y;  // (32,8)
#pragma unroll
  for (int j = 0; j < 4; j++) {
    int k = k0 + ty + j * 8;
    t[ty + j * 8][tx] = f2bf(W[(size_t)k * DD + n0 + tx]);
  }
  __syncthreads();
#pragma unroll
  for (int j = 0; j < 4; j++) {
    int n = ty + j * 8;
    O[(size_t)(n0 + n) * DD + k0 + tx] = t[tx][n];
  }
}

// ------------------------------------------- transpose V [S,ldv slice] -> Vt [D,S] per batch
__global__ __launch_bounds__(256) void transpose_v(const ushort* __restrict__ V, int ldv,
                                                   ushort* __restrict__ Vt) {
  const int b = blockIdx.z;
  const ushort* Vb = V + (size_t)b * SS * ldv;
  ushort* Ob = Vt + (size_t)b * DD * SS;
  __shared__ ushort t[32][33];
  const int d0 = blockIdx.x * 32, s0 = blockIdx.y * 32;
  const int tx = threadIdx.x, ty = threadIdx.y;
#pragma unroll
  for (int j = 0; j < 4; j++) {
    int s = s0 + ty + j * 8;
    t[ty + j * 8][tx] = Vb[(size_t)s * ldv + d0 + tx];
  }
  __syncthreads();
#pragma unroll
  for (int j = 0; j < 4; j++) {
    int d = ty + j * 8;
    Ob[(size_t)(d0 + d) * SS + s0 + tx] = t[tx][d];
  }
}

// ---------------------------------------------------------------- 2-phase/K-tile MFMA GEMM
// C[M,N] = A[M,K](bf16 rm) @ Bt[N,K](bf16 rm)^T. Tile 256x128, BK=64, 512 thr = 8 waves 4Mx2N
// (wave C-tile 64x64 = 16 frags -> 16 MFMA per phase). LDS: A [2buf][2kh][256x32],
// B [2buf][2kh][128x32] = 96KB. Phase p1: read A-Kh0 + B-Kh0 + B-Kh1 (12xb128), stage
// A-Kh1(t+1); p2: read A-Kh1 (4xb128), stage B0/A0/B1(t+2), gate vmcnt(4) (counted, never 0
// mid-loop). FIFO: at t.p2's gate the 4 youngest loads are t+2's -> all of t+1 retired.
#define MFMA16(AV, BV)                                                       \
  do {                                                                       \
    __builtin_amdgcn_s_setprio(1);                                           \
    _Pragma("unroll") for (int i_ = 0; i_ < 4; i_++) {                       \
      _Pragma("unroll") for (int n_ = 0; n_ < 4; n_++) {                     \
        acc[i_][n_] = __builtin_amdgcn_mfma_f32_16x16x32_bf16(               \
            AV[i_], BV[n_], acc[i_][n_], 0, 0, 0);                           \
      }                                                                      \
    }                                                                        \
    __builtin_amdgcn_s_setprio(0);                                           \
  } while (0)

template <bool CAUSAL, bool KCLIP, bool OUT_BF16>
__global__ __launch_bounds__(512) void gemm2p(const ushort* __restrict__ A, int lda, size_t strA,
                                              const ushort* __restrict__ Bt, int ldb, size_t strB,
                                              void* __restrict__ C, int ldc, size_t strC, int K) {
  constexpr int BM = 256, BN = 128;
  // XCD-chunked bijective block swizzle (m204 form)
  const int gx = gridDim.x;
  const int nwg = gx * gridDim.y;
  int flat = blockIdx.y * gx + blockIdx.x;
  {
    int q = nwg >> 3, r = nwg & 7;
    int xcd = flat & 7, idx = flat >> 3;
    flat = (xcd < r ? xcd * (q + 1) : r * (q + 1) + (xcd - r) * q) + idx;
  }
  const int nb = flat % gx, mb = flat / gx, bz = blockIdx.z;
  if (CAUSAL && nb * BN > mb * BM + (BM - 1)) return;

  __shared__ char ldsA[2][2][16384];  // [dbuf][kh][256 rows x 32 elem]
  __shared__ char ldsB[2][2][8192];   // [dbuf][kh][128 rows x 32 elem]

  const int tid = threadIdx.x;
  const int lane = tid & 63, wid = tid >> 6;
  const int wr = wid >> 1, wc = wid & 1;  // 4M x 2N waves; wave tile 64x64
  const int fr = lane & 15, qq = lane >> 4;
  const int kxor = (qq * 16) ^ (((fr >> 3) & 1) << 5);  // swizzled k-byte within 64B row

  const ushort* Ag = A + (size_t)bz * strA + (size_t)mb * BM * lda;
  const ushort* Bg = Bt + (size_t)bz * strB + (size_t)nb * BN * ldb;
  // staging source (inverse swizzle): thread t -> row t>>2, colbyte ((t&3)*16)^(((t>>5)&1)<<5)
  const int srcColB = (((tid & 3) * 16) ^ (((tid >> 5) & 1) << 5)) >> 1;  // in elems
  const ushort* Ag_t = Ag + (size_t)(tid >> 2) * lda + srcColB;
  const ushort* Bg_t = Bg + (size_t)(tid >> 2) * ldb + srcColB;

  int kEnd = KCLIP ? (mb + 1) * BM : K;
  if (kEnd > K) kEnd = K;
  const int NT = kEnd >> 6;

  auto stageA = [&](int buf, int kh, int kt) {
#pragma unroll
    for (int j = 0; j < 2; j++)
      gload_lds16(Ag_t + (size_t)(j * 128) * lda + kt * 64 + kh * 32,
                  &ldsA[buf][kh][(tid + j * 512) * 16]);
  };
  auto stageB = [&](int buf, int kh, int kt) {
    gload_lds16(Bg_t + kt * 64 + kh * 32, &ldsB[buf][kh][tid * 16]);
  };
  auto ldA4 = [&](int buf, int kh, bf16x8* o) {
#pragma unroll
    for (int i = 0; i < 4; i++)
      o[i] = *(const bf16x8*)(&ldsA[buf][kh][0] +
                              ((wr * 64 + i * 16 + fr) << 6) + kxor);
  };
  auto ldB4 = [&](int buf, int kh, bf16x8* o) {
#pragma unroll
    for (int n = 0; n < 4; n++)
      o[n] = *(const bf16x8*)(&ldsB[buf][kh][0] +
                              ((wc * 64 + n * 16 + fr) << 6) + kxor);
  };

  // prologue: t0 full (6 loads) + t1 {B0,A0,B1} (4; A1(t1) staged at t0.p1)
  stageA(0, 0, 0); stageA(0, 1, 0); stageB(0, 0, 0); stageB(0, 1, 0);
  if (NT > 1) { stageB(1, 0, 1); stageA(1, 0, 1); stageB(1, 1, 1); }
  __builtin_amdgcn_sched_barrier(0);
  if (NT > 1) asm volatile("s_waitcnt vmcnt(4)" ::: "memory");
  else        asm volatile("s_waitcnt vmcnt(0)" ::: "memory");
  fence_bar();

  f32x4 acc[4][4] = {};

  for (int t = 0; t < NT; ++t) {
    const int cur = t & 1;
    bf16x8 a0[4], a1[4], b0[4], b1[4];
    // ---- p1: ks0. Read A-Kh0 + BOTH B halves; stage A-Kh1(t+1) into free buffer.
    ldA4(cur, 0, a0);
    ldB4(cur, 0, b0);
    ldB4(cur, 1, b1);
    if (t + 1 < NT) stageA(cur ^ 1, 1, t + 1);
    fence_bar();
    asm volatile("s_waitcnt lgkmcnt(0)" ::: "memory");
    __builtin_amdgcn_sched_barrier(0);
    MFMA16(a0, b0);
    fence_bar();
    // ---- p2: ks1. Read A-Kh1 (B-Kh1 already in regs); stage t+2 units into consumed
    //      regions of cur buf; counted gate.
    ldA4(cur, 1, a1);
    if (t + 2 < NT) {
      stageB(cur, 0, t + 2);
      stageA(cur, 0, t + 2);
      stageB(cur, 1, t + 2);
      __builtin_amdgcn_sched_barrier(0);
      asm volatile("s_waitcnt vmcnt(4)" ::: "memory");  // retires all of t+1
    } else {
      asm volatile("s_waitcnt vmcnt(0)" ::: "memory");  // tail drain
    }
    fence_bar();
    asm volatile("s_waitcnt lgkmcnt(0)" ::: "memory");
    __builtin_amdgcn_sched_barrier(0);
    MFMA16(a1, b1);
    fence_bar();
  }

  // epilogue: C/D mapping col=lane&15, row=(lane>>4)*4+reg
  const int col0 = nb * BN + wc * 64 + fr;
  const int row00 = mb * BM + wr * 64 + qq * 4;
  if (OUT_BF16) {
    ushort* Cb = (ushort*)C + (size_t)bz * strC;
#pragma unroll
    for (int i = 0; i < 4; i++)
#pragma unroll
      for (int rr = 0; rr < 4; rr++) {
        size_t ro = (size_t)(row00 + i * 16 + rr) * ldc;
#pragma unroll
        for (int n = 0; n < 4; n++) Cb[ro + col0 + n * 16] = f2bf(acc[i][n][rr]);
      }
  } else {
    float* Cb = (float*)C + (size_t)bz * strC;
#pragma unroll
    for (int i = 0; i < 4; i++)
#pragma unroll
      for (int rr = 0; rr < 4; rr++) {
        size_t ro = (size_t)(row00 + i * 16 + rr) * ldc;
#pragma unroll
        for (int n = 0; n < 4; n++) Cb[ro + col0 + n * 16] = acc[i][n][rr];
      }
  }
}

// ---------------------------------------------------------------- single-pass causal softmax
// Sc: [B*S, S] bf16 raw scores (valid cols <= r). P: [B*S, S] bf16 normalized, zeros above diag.
__global__ __launch_bounds__(256) void softmax_causal(const ushort* __restrict__ Sc,
                                                      ushort* __restrict__ P) {
  const int row = blockIdx.x;
  const int r = row & (SS - 1);
  const ushort* srow = Sc + (size_t)row * SS;
  ushort* prow = P + (size_t)row * SS;
  const int tid = threadIdx.x;
  __shared__ float buf[SS];
  __shared__ float redm[4], reds[4];
  const float scale = 0.03125f;  // 1/sqrt(1024)
  const int nc = (r >> 3) + 1;   // 8-wide chunks containing valid cols

  float mx = -3.0e38f;
  for (int c8 = tid; c8 < nc; c8 += 256) {
    u16x8 v = ((const u16x8*)srow)[c8];
    int c = c8 * 8;
#pragma unroll
    for (int k = 0; k < 8; k++) {
      float f = __uint_as_float(((unsigned)v[k]) << 16);
      f = (c + k <= r) ? f * scale : -3.0e38f;
      buf[c + k] = f;
      mx = fmaxf(mx, f);
    }
  }
  const int lane = tid & 63, wid = tid >> 6;
#pragma unroll
  for (int off = 32; off > 0; off >>= 1) mx = fmaxf(mx, __shfl_down(mx, off));
  if (lane == 0) redm[wid] = mx;
  __syncthreads();
  mx = fmaxf(fmaxf(redm[0], redm[1]), fmaxf(redm[2], redm[3]));

  float sum = 0.f;
  for (int c = tid; c < nc * 8; c += 256) {
    float e = __expf(buf[c] - mx);
    buf[c] = e;
    sum += e;
  }
#pragma unroll
  for (int off = 32; off > 0; off >>= 1) sum += __shfl_down(sum, off);
  if (lane == 0) reds[wid] = sum;
  __syncthreads();
  sum = reds[0] + reds[1] + reds[2] + reds[3];
  const float inv = 1.0f / sum;
  __syncthreads();  // buf writes complete before reads below

  const int zs = nc * 8;
  for (int c8 = tid; c8 < SS / 8; c8 += 256) {
    int c = c8 * 8;
    u16x8 o;
    if (c < zs) {
#pragma unroll
      for (int k = 0; k < 8; k++) o[k] = f2bf(buf[c + k] * inv);
    } else {
#pragma unroll
      for (int k = 0; k < 8; k++) o[k] = 0;
    }
    ((u16x8*)prow)[c8] = o;
  }
}

// ---------------------------------------------------------------- launch
extern "C" void kernel_launch(void* const* d_in, const int* in_sizes, int n_in,
                              void* d_out, int out_size, void* d_ws, size_t ws_size,
                              hipStream_t stream) {
  const float* x = (const float*)d_in[0];
  const float* Wq = (const float*)d_in[1];
  const float* Wk = (const float*)d_in[2];
  const float* Wv = (const float*)d_in[3];

  char* ws = (char*)d_ws;
  // layout: xb @0 (16.7MB, reused by Vt) | Wt @16777216 (6.3MB) | QKV @23068672 (50.3MB,
  // reused by P) | Sc @73400320 (33.5MB bf16)
  ushort* xb = (ushort*)(ws);
  ushort* Wt = (ushort*)(ws + 16777216);
  ushort* QKV = (ushort*)(ws + 23068672);
  ushort* Sc = (ushort*)(ws + 73400320);
  ushort* P = (ushort*)(ws + 23068672);
  ushort* Vt = (ushort*)(ws);

  const size_t SD = (size_t)SS * DD;
  const size_t S2 = (size_t)SS * SS;
  const size_t SQ = (size_t)SS * 3072;

  cast_x_kernel<<<(BB * SS * DD) / (256 * 8), 256, 0, stream>>>(x, xb);
  cast_transpose_w<<<dim3(DD / 32, DD / 32, 3), dim3(32, 8), 0, stream>>>(Wq, Wk, Wv, Wt);
  // QKV projection: [8192,3072] = xb @ Wt^T   (768 blocks = 3 full rounds)
  gemm2p<false, false, true><<<dim3(3072 / 128, (BB * SS) / 256, 1), 512, 0, stream>>>(
      xb, DD, 0, Wt, DD, 0, QKV, 3072, 0, DD);
  transpose_v<<<dim3(DD / 32, SS / 32, BB), dim3(32, 8), 0, stream>>>(QKV + 2048, 3072, Vt);
  // scores = Q @ K^T (bf16 out, causal skip)   (288 active blocks)
  gemm2p<true, false, true><<<dim3(SS / 128, SS / 256, BB), 512, 0, stream>>>(
      QKV, 3072, SQ, QKV + 1024, 3072, SQ, Sc, SS, S2, DD);
  softmax_causal<<<BB * SS, 256, 0, stream>>>(Sc, P);
  // out = P @ Vt^T (f32), k-clipped   (256 blocks = 1 full round)
  gemm2p<false, true, false><<<dim3(DD / 128, SS / 256, BB), 512, 0, stream>>>(
      P, SS, S2, Vt, SS, SD, d_out, DD, SD, SS);

  (void)in_sizes; (void)n_in; (void)out_size; (void)ws_size;
}

// Round 5
// 203.132 us; speedup vs baseline: 1.0325x; 1.0161x over previous
//
#include <hip/hip_runtime.h>
#include <hip/hip_bf16.h>

// B=4, S=2048, D=1024 causal attention, fp32 in/out, bf16 MFMA compute.
#define BB 4
#define SS 2048
#define DD 1024

typedef __attribute__((ext_vector_type(8))) short bf16x8;
typedef __attribute__((ext_vector_type(4))) float f32x4;
typedef __attribute__((ext_vector_type(8))) unsigned short u16x8;

__device__ __forceinline__ ushort f2bf(float f) {
  unsigned u = __float_as_uint(f);
  unsigned r = (u + 0x7fffu + ((u >> 16) & 1u)) >> 16;  // RNE
  return (ushort)r;
}

__device__ __forceinline__ void gload_lds16(const void* g, void* l) {
  __builtin_amdgcn_global_load_lds(
      (const __attribute__((address_space(1))) void*)g,
      (__attribute__((address_space(3))) void*)l, 16, 0, 0);
}

__device__ __forceinline__ void fence_bar() {
  __builtin_amdgcn_sched_barrier(0);
  __builtin_amdgcn_s_barrier();
  __builtin_amdgcn_sched_barrier(0);
}

// ---------------------------------------------------------------- cast x -> bf16
__global__ __launch_bounds__(256) void cast_x_kernel(const float* __restrict__ x,
                                                     ushort* __restrict__ xb) {
  const int i = blockIdx.x * 256 + threadIdx.x;
  const float4 a = ((const float4*)x)[2 * i];
  const float4 b = ((const float4*)x)[2 * i + 1];
  ushort4 o0, o1;
  o0.x = f2bf(a.x); o0.y = f2bf(a.y); o0.z = f2bf(a.z); o0.w = f2bf(a.w);
  o1.x = f2bf(b.x); o1.y = f2bf(b.y); o1.z = f2bf(b.z); o1.w = f2bf(b.w);
  ((ushort4*)xb)[2 * i] = o0;
  ((ushort4*)xb)[2 * i + 1] = o1;
}

// ------------------------------------------- cast + transpose W [K,N] -> Wt [N,K] bf16
__global__ __launch_bounds__(256) void cast_transpose_w(const float* __restrict__ W0,
                                                        const float* __restrict__ W1,
                                                        const float* __restrict__ W2,
                                                        ushort* __restrict__ Wt) {
  const float* W = blockIdx.z == 0 ? W0 : (blockIdx.z == 1 ? W1 : W2);
  ushort* O = Wt + (size_t)blockIdx.z * DD * DD;
  __shared__ ushort t[32][33];
  const int n0 = blockIdx.x * 32, k0 = blockIdx.y * 32;
  const int tx = threadIdx.x, ty = threadIdx.y;  // (32,8)
#pragma unroll
  for (int j = 0; j < 4; j++) {
    int k = k0 + ty + j * 8;
    t[ty + j * 8][tx] = f2bf(W[(size_t)k * DD + n0 + tx]);
  }
  __syncthreads();
#pragma unroll
  for (int j = 0; j < 4; j++) {
    int n = ty + j * 8;
    O[(size_t)(n0 + n) * DD + k0 + tx] = t[tx][n];
  }
}

// ------------------------------------------- transpose V [S,ldv slice] -> Vt [D,S] per batch
__global__ __launch_bounds__(256) void transpose_v(const ushort* __restrict__ V, int ldv,
                                                   ushort* __restrict__ Vt) {
  const int b = blockIdx.z;
  const ushort* Vb = V + (size_t)b * SS * ldv;
  ushort* Ob = Vt + (size_t)b * DD * SS;
  __shared__ ushort t[32][33];
  const int d0 = blockIdx.x * 32, s0 = blockIdx.y * 32;
  const int tx = threadIdx.x, ty = threadIdx.y;
#pragma unroll
  for (int j = 0; j < 4; j++) {
    int s = s0 + ty + j * 8;
    t[ty + j * 8][tx] = Vb[(size_t)s * ldv + d0 + tx];
  }
  __syncthreads();
#pragma unroll
  for (int j = 0; j < 4; j++) {
    int d = ty + j * 8;
    Ob[(size_t)(d0 + d) * SS + s0 + tx] = t[tx][d];
  }
}

// ---------------------------------------------------------------- 2-phase/K-tile MFMA GEMM
// C[M,N] = A[M,K](bf16 rm) @ Bt[N,K](bf16 rm)^T. Tile 256x128, BK=64, 512 thr = 8 waves 4Mx2N.
// Deep-slack counted gates (all waited loads were issued >=3 phases earlier):
//   issue order/tile t: [t.p1: A1(t+1) x2] [t.p2: B0,A0x2,B1(t+2) x4]
//   G2 (before p2's A1 read):  vmcnt(6) retires A1(t)        (issued (t-1).p1)
//   G1 (end of tile):          vmcnt(6) retires B0A0B1(t+1)  (issued (t-1).p2)
// Each gate is followed by an s_barrier before dependent ds_reads (vmcnt is per-wave).
// WAR-safety: regions staged at a phase were last read one barrier earlier by all waves.
#define MFMA16(AV, BV)                                                       \
  do {                                                                       \
    __builtin_amdgcn_s_setprio(1);                                           \
    _Pragma("unroll") for (int i_ = 0; i_ < 4; i_++) {                       \
      _Pragma("unroll") for (int n_ = 0; n_ < 4; n_++) {                     \
        acc[i_][n_] = __builtin_amdgcn_mfma_f32_16x16x32_bf16(               \
            AV[i_], BV[n_], acc[i_][n_], 0, 0, 0);                           \
      }                                                                      \
    }                                                                        \
    __builtin_amdgcn_s_setprio(0);                                           \
  } while (0)

template <bool TRI, bool KCLIP, bool OUT_BF16>
__global__ __launch_bounds__(512) void gemm2p(const ushort* __restrict__ A, int lda, size_t strA,
                                              const ushort* __restrict__ Bt, int ldb, size_t strB,
                                              void* __restrict__ C, int ldc, size_t strC, int K) {
  constexpr int BM = 256, BN = 128;
  int nb, mb, bz;
  if (TRI) {
    // triangular grid: per bz, i in [0,72): mb = tri-row, nb in [0, 2(mb+1)).
    // 288 total; XCD-chunk (288 = 8*36) then decode.
    int flat = blockIdx.x + 72 * blockIdx.z;
    flat = (flat & 7) * 36 + (flat >> 3);
    bz = flat / 72;
    int i = flat % 72;
    mb = (int)((sqrtf(4.f * i + 1.f) - 1.f) * 0.5f);
    while ((mb + 1) * (mb + 2) <= i) ++mb;
    while (mb * (mb + 1) > i) --mb;
    nb = i - mb * (mb + 1);
  } else {
    const int gx = gridDim.x;
    const int nwg = gx * gridDim.y;
    int flat = blockIdx.y * gx + blockIdx.x;
    int q = nwg >> 3, r = nwg & 7;
    int xcd = flat & 7, idx = flat >> 3;
    flat = (xcd < r ? xcd * (q + 1) : r * (q + 1) + (xcd - r) * q) + idx;
    nb = flat % gx;
    mb = flat / gx;
    bz = blockIdx.z;
  }

  __shared__ char ldsA[2][2][16384];  // [dbuf][kh][256 rows x 32 elem]
  __shared__ char ldsB[2][2][8192];   // [dbuf][kh][128 rows x 32 elem]

  const int tid = threadIdx.x;
  const int lane = tid & 63, wid = tid >> 6;
  const int wr = wid >> 1, wc = wid & 1;  // 4M x 2N waves; wave tile 64x64
  const int fr = lane & 15, qq = lane >> 4;
  const int kxor = (qq * 16) ^ (((fr >> 3) & 1) << 5);  // swizzled k-byte within 64B row

  const ushort* Ag = A + (size_t)bz * strA + (size_t)mb * BM * lda;
  const ushort* Bg = Bt + (size_t)bz * strB + (size_t)nb * BN * ldb;
  // staging source (inverse swizzle): thread t -> row t>>2, colbyte ((t&3)*16)^(((t>>5)&1)<<5)
  const int srcColB = (((tid & 3) * 16) ^ (((tid >> 5) & 1) << 5)) >> 1;  // in elems
  const ushort* Ag_t = Ag + (size_t)(tid >> 2) * lda + srcColB;
  const ushort* Bg_t = Bg + (size_t)(tid >> 2) * ldb + srcColB;

  int kEnd = KCLIP ? (mb + 1) * BM : K;
  if (kEnd > K) kEnd = K;
  const int NT = kEnd >> 6;

  auto stageA = [&](int buf, int kh, int kt) {
#pragma unroll
    for (int j = 0; j < 2; j++)
      gload_lds16(Ag_t + (size_t)(j * 128) * lda + kt * 64 + kh * 32,
                  &ldsA[buf][kh][(tid + j * 512) * 16]);
  };
  auto stageB = [&](int buf, int kh, int kt) {
    gload_lds16(Bg_t + kt * 64 + kh * 32, &ldsB[buf][kh][tid * 16]);
  };
  auto ldA4 = [&](int buf, int kh, bf16x8* o) {
#pragma unroll
    for (int i = 0; i < 4; i++)
      o[i] = *(const bf16x8*)(&ldsA[buf][kh][0] +
                              ((wr * 64 + i * 16 + fr) << 6) + kxor);
  };
  auto ldB4 = [&](int buf, int kh, bf16x8* o) {
#pragma unroll
    for (int n = 0; n < 4; n++)
      o[n] = *(const bf16x8*)(&ldsB[buf][kh][0] +
                              ((wc * 64 + n * 16 + fr) << 6) + kxor);
  };

  // prologue: t0 full (6 loads) + t1 {B0,A0,B1} (4 loads; A1(t1) staged at t0.p1)
  stageA(0, 0, 0); stageA(0, 1, 0); stageB(0, 0, 0); stageB(0, 1, 0);
  if (NT > 1) { stageB(1, 0, 1); stageA(1, 0, 1); stageB(1, 1, 1); }
  __builtin_amdgcn_sched_barrier(0);
  if (NT > 1) asm volatile("s_waitcnt vmcnt(4)" ::: "memory");
  else        asm volatile("s_waitcnt vmcnt(0)" ::: "memory");
  fence_bar();

  f32x4 acc[4][4] = {};

  for (int t = 0; t < NT; ++t) {
    const int cur = t & 1;
    bf16x8 a0[4], a1[4], b0[4], b1[4];
    // ---- p1: read A-Kh0 + BOTH B halves (B1 must be read before p2 overwrites it);
    //      stage A1(t+1) into free buffer (its region last read at (t-1).p2).
    ldA4(cur, 0, a0);
    ldB4(cur, 0, b0);
    ldB4(cur, 1, b1);
    if (t + 1 < NT) stageA(cur ^ 1, 1, t + 1);
    fence_bar();  // barrier 1
    asm volatile("s_waitcnt lgkmcnt(0)" ::: "memory");
    __builtin_amdgcn_sched_barrier(0);
    MFMA16(a0, b0);
    // ---- G2: A1(t) landed (issued (t-1).p1; 6 younger loads in flight)
    __builtin_amdgcn_sched_barrier(0);
    if (t + 1 < NT) asm volatile("s_waitcnt vmcnt(6)" ::: "memory");
    else            asm volatile("s_waitcnt vmcnt(0)" ::: "memory");
    fence_bar();  // barrier 2: publishes A1(t) slices; also ends all waves' p1 reads
    // ---- p2: read A-Kh1; stage t+2 units into regions consumed at p1.
    ldA4(cur, 1, a1);
    if (t + 2 < NT) {
      stageB(cur, 0, t + 2);
      stageA(cur, 0, t + 2);
      stageB(cur, 1, t + 2);
    }
    // ---- G1: B0,A0,B1(t+1) landed (issued (t-1).p2)
    __builtin_amdgcn_sched_barrier(0);
    if (t + 2 < NT)      asm volatile("s_waitcnt vmcnt(6)" ::: "memory");
    else if (t + 1 < NT) asm volatile("s_waitcnt vmcnt(2)" ::: "memory");
    fence_bar();  // barrier 3: publishes next tile's p1 units; ends p2 stage hazards
    asm volatile("s_waitcnt lgkmcnt(0)" ::: "memory");
    __builtin_amdgcn_sched_barrier(0);
    MFMA16(a1, b1);
    fence_bar();  // barrier 4
  }

  // epilogue: C/D mapping col=lane&15, row=(lane>>4)*4+reg
  const int col0 = nb * BN + wc * 64 + fr;
  const int row00 = mb * BM + wr * 64 + qq * 4;
  if (OUT_BF16) {
    ushort* Cb = (ushort*)C + (size_t)bz * strC;
#pragma unroll
    for (int i = 0; i < 4; i++)
#pragma unroll
      for (int rr = 0; rr < 4; rr++) {
        size_t ro = (size_t)(row00 + i * 16 + rr) * ldc;
#pragma unroll
        for (int n = 0; n < 4; n++) Cb[ro + col0 + n * 16] = f2bf(acc[i][n][rr]);
      }
  } else {
    float* Cb = (float*)C + (size_t)bz * strC;
#pragma unroll
    for (int i = 0; i < 4; i++)
#pragma unroll
      for (int rr = 0; rr < 4; rr++) {
        size_t ro = (size_t)(row00 + i * 16 + rr) * ldc;
#pragma unroll
        for (int n = 0; n < 4; n++) Cb[ro + col0 + n * 16] = acc[i][n][rr];
      }
  }
}

// ---------------------------------------------------------------- single-pass causal softmax
__global__ __launch_bounds__(256) void softmax_causal(const ushort* __restrict__ Sc,
                                                      ushort* __restrict__ P) {
  const int row = blockIdx.x;
  const int r = row & (SS - 1);
  const ushort* srow = Sc + (size_t)row * SS;
  ushort* prow = P + (size_t)row * SS;
  const int tid = threadIdx.x;
  __shared__ float buf[SS];
  __shared__ float redm[4], reds[4];
  const float scale = 0.03125f;  // 1/sqrt(1024)
  const int nc = (r >> 3) + 1;   // 8-wide chunks containing valid cols

  float mx = -3.0e38f;
  for (int c8 = tid; c8 < nc; c8 += 256) {
    u16x8 v = ((const u16x8*)srow)[c8];
    int c = c8 * 8;
#pragma unroll
    for (int k = 0; k < 8; k++) {
      float f = __uint_as_float(((unsigned)v[k]) << 16);
      f = (c + k <= r) ? f * scale : -3.0e38f;
      buf[c + k] = f;
      mx = fmaxf(mx, f);
    }
  }
  const int lane = tid & 63, wid = tid >> 6;
#pragma unroll
  for (int off = 32; off > 0; off >>= 1) mx = fmaxf(mx, __shfl_down(mx, off));
  if (lane == 0) redm[wid] = mx;
  __syncthreads();
  mx = fmaxf(fmaxf(redm[0], redm[1]), fmaxf(redm[2], redm[3]));

  float sum = 0.f;
  for (int c = tid; c < nc * 8; c += 256) {
    float e = __expf(buf[c] - mx);
    buf[c] = e;
    sum += e;
  }
#pragma unroll
  for (int off = 32; off > 0; off >>= 1) sum += __shfl_down(sum, off);
  if (lane == 0) reds[wid] = sum;
  __syncthreads();
  sum = reds[0] + reds[1] + reds[2] + reds[3];
  const float inv = 1.0f / sum;
  __syncthreads();

  const int zs = nc * 8;
  for (int c8 = tid; c8 < SS / 8; c8 += 256) {
    int c = c8 * 8;
    u16x8 o;
    if (c < zs) {
#pragma unroll
      for (int k = 0; k < 8; k++) o[k] = f2bf(buf[c + k] * inv);
    } else {
#pragma unroll
      for (int k = 0; k < 8; k++) o[k] = 0;
    }
    ((u16x8*)prow)[c8] = o;
  }
}

// ---------------------------------------------------------------- launch
extern "C" void kernel_launch(void* const* d_in, const int* in_sizes, int n_in,
                              void* d_out, int out_size, void* d_ws, size_t ws_size,
                              hipStream_t stream) {
  const float* x = (const float*)d_in[0];
  const float* Wq = (const float*)d_in[1];
  const float* Wk = (const float*)d_in[2];
  const float* Wv = (const float*)d_in[3];

  char* ws = (char*)d_ws;
  // layout: xb @0 (16.7MB, reused by Vt) | Wt @16777216 (6.3MB) | QKV @23068672 (50.3MB,
  // reused by P) | Sc @73400320 (33.5MB bf16)
  ushort* xb = (ushort*)(ws);
  ushort* Wt = (ushort*)(ws + 16777216);
  ushort* QKV = (ushort*)(ws + 23068672);
  ushort* Sc = (ushort*)(ws + 73400320);
  ushort* P = (ushort*)(ws + 23068672);
  ushort* Vt = (ushort*)(ws);

  const size_t SD = (size_t)SS * DD;
  const size_t S2 = (size_t)SS * SS;
  const size_t SQ = (size_t)SS * 3072;

  cast_x_kernel<<<(BB * SS * DD) / (256 * 8), 256, 0, stream>>>(x, xb);
  cast_transpose_w<<<dim3(DD / 32, DD / 32, 3), dim3(32, 8), 0, stream>>>(Wq, Wk, Wv, Wt);
  // QKV projection: [8192,3072] = xb @ Wt^T   (768 blocks = 3 full rounds)
  gemm2p<false, false, true><<<dim3(3072 / 128, (BB * SS) / 256, 1), 512, 0, stream>>>(
      xb, DD, 0, Wt, DD, 0, QKV, 3072, 0, DD);
  transpose_v<<<dim3(DD / 32, SS / 32, BB), dim3(32, 8), 0, stream>>>(QKV + 2048, 3072, Vt);
  // scores = Q @ K^T (bf16 out), triangular grid: exactly the 288 active blocks
  gemm2p<true, false, true><<<dim3(72, 1, BB), 512, 0, stream>>>(
      QKV, 3072, SQ, QKV + 1024, 3072, SQ, Sc, SS, S2, DD);
  softmax_causal<<<BB * SS, 256, 0, stream>>>(Sc, P);
  // out = P @ Vt^T (f32), k-clipped   (256 blocks = 1 full round)
  gemm2p<false, true, false><<<dim3(DD / 128, SS / 256, BB), 512, 0, stream>>>(
      P, SS, S2, Vt, SS, SD, d_out, DD, SD, SS);

  (void)in_sizes; (void)n_in; (void)out_size; (void)ws_size;
}